// Round 10
// baseline (291.274 us; speedup 1.0000x reference)
//
#include <hip/hip_runtime.h>
#include <hip/hip_bf16.h>
#include <math.h>

// Problem constants
#define B_ 2
#define S_ 2048
#define H_ 1024
#define A_ 1024
#define NH_ 16
#define HD_ 64
#define H3_ 3072
#define EPS_ 1e-5f

typedef __attribute__((ext_vector_type(8))) short short8;   // 8 bf16 in 4 VGPRs
typedef __attribute__((ext_vector_type(4))) float floatx4;  // MFMA accumulator

__device__ inline unsigned short f2bf(float x) {
    union { float f; unsigned u; } v; v.f = x;
    unsigned r = v.u + 0x7fffu + ((v.u >> 16) & 1u);   // RNE
    return (unsigned short)(r >> 16);
}

__device__ inline float bf2f(unsigned short u) {
    union { unsigned u; float f; } v; v.u = ((unsigned)u) << 16;
    return v.f;
}

// packed f32x2 -> bf16x2 (v_cvt_pk_bf16_f32 on gfx950)
__device__ inline unsigned pk_bf16(float a, float b) {
    union { __hip_bfloat162 h; unsigned u; } v;
    v.h = __float22bfloat162_rn(make_float2(a, b));
    return v.u;
}

// async global->LDS, 16B per lane; LDS dst must be wave-uniform base + lane*16
__device__ inline void gld_lds16(const void* g, void* l) {
    __builtin_amdgcn_global_load_lds(
        (const __attribute__((address_space(1))) unsigned int*)g,
        (__attribute__((address_space(3))) unsigned int*)l, 16, 0, 0);
}

// block-padded attention tile layout: 8-row blocks (1024 B) + 64 B pad each.
// row r (0..63), 64 ushorts/row: offset = (r>>3)*544 + (r&7)*64   [ushorts]
#define TBLK(r) ((((r) >> 3) * 544) + (((r) & 7) * 64))

// ---------------------------------------------------------------------------
// Kernel 0: fp32 -> bf16 cast (weights), 8 elems/thread
// ---------------------------------------------------------------------------
__global__ __launch_bounds__(256) void cast_bf16_kernel(
    const float* __restrict__ in, unsigned short* __restrict__ out, int n)
{
    int i = (blockIdx.x * 256 + threadIdx.x) * 8;
    if (i >= n) return;
    float4 a = *(const float4*)(in + i);
    float4 b = *(const float4*)(in + i + 4);
    uint4 o;
    o.x = pk_bf16(a.x, a.y);
    o.y = pk_bf16(a.z, a.w);
    o.z = pk_bf16(b.x, b.y);
    o.w = pk_bf16(b.z, b.w);
    *(uint4*)(out + i) = o;
}

// ---------------------------------------------------------------------------
// Kernel 1: mod = silu(ada_cond) @ mod_w^T + mod_b     [B, 3H]
// ---------------------------------------------------------------------------
__global__ __launch_bounds__(256) void mod_gemv_kernel(
    const float* __restrict__ ada, const float* __restrict__ mod_w,
    const float* __restrict__ mod_b, float* __restrict__ mod)
{
    int wid = threadIdx.x >> 6;
    int lane = threadIdx.x & 63;
    int idx = blockIdx.x * 4 + wid;       // 0 .. B*3H-1
    int b = idx / H3_;
    int j = idx % H3_;
    const float* ar = ada + (size_t)b * A_;
    const float* wr = mod_w + (size_t)j * A_;
    float acc = 0.f;
    for (int a = lane; a < A_; a += 64) {
        float av = ar[a];
        float sv = av / (1.f + __expf(-av));   // silu
        acc += sv * wr[a];
    }
    #pragma unroll
    for (int m = 1; m < 64; m <<= 1) acc += __shfl_xor(acc, m);
    if (lane == 0) mod[idx] = acc + mod_b[j];
}

// ---------------------------------------------------------------------------
// Kernel 2: h = layernorm(x)*ln_w * (scale+1) + shift -> bf16  [B,S,H]
// ---------------------------------------------------------------------------
__global__ __launch_bounds__(256) void ln_mod_kernel(
    const float* __restrict__ x, const float* __restrict__ ln_w,
    const float* __restrict__ mod, unsigned short* __restrict__ hout)
{
    int row = blockIdx.x;          // over B*S
    int b = row >> 11;             // row / 2048
    const float* xr = x + (size_t)row * H_;
    int t = threadIdx.x;
    float4 xv = *(const float4*)(xr + t * 4);
    float s1 = xv.x + xv.y + xv.z + xv.w;
    float s2 = xv.x*xv.x + xv.y*xv.y + xv.z*xv.z + xv.w*xv.w;
    #pragma unroll
    for (int m = 1; m < 64; m <<= 1) { s1 += __shfl_xor(s1, m); s2 += __shfl_xor(s2, m); }
    __shared__ float r1[4], r2[4];
    int wid = t >> 6, lane = t & 63;
    if (lane == 0) { r1[wid] = s1; r2[wid] = s2; }
    __syncthreads();
    s1 = r1[0] + r1[1] + r1[2] + r1[3];
    s2 = r2[0] + r2[1] + r2[2] + r2[3];
    float mean = s1 * (1.f / H_);
    float var  = s2 * (1.f / H_) - mean * mean;
    float rstd = rsqrtf(var + EPS_);
    const float* mrow = mod + (size_t)b * H3_;
    float4 wv = *(const float4*)(ln_w + t * 4);
    float4 sc = *(const float4*)(mrow + t * 4);
    float4 sh = *(const float4*)(mrow + H_ + t * 4);
    float4 hv;
    hv.x = (xv.x - mean) * rstd * wv.x * (sc.x + 1.f) + sh.x;
    hv.y = (xv.y - mean) * rstd * wv.y * (sc.y + 1.f) + sh.y;
    hv.z = (xv.z - mean) * rstd * wv.z * (sc.z + 1.f) + sh.z;
    hv.w = (xv.w - mean) * rstd * wv.w * (sc.w + 1.f) + sh.w;
    uint2 o;
    o.x = pk_bf16(hv.x, hv.y);
    o.y = pk_bf16(hv.z, hv.w);
    *(uint2*)(hout + (size_t)row * H_ + t * 4) = o;
}

// ---------------------------------------------------------------------------
// Kernel 3/6: bf16 MFMA GEMM  C[M,N] = A[M,K] @ B[N,K]^T  (m97 structure)
// out_bf16: C written as bf16 (ushort) instead of fp32.
// ---------------------------------------------------------------------------
__global__ __launch_bounds__(256) void gemm_bt_bf16_kernel(
    const unsigned short* __restrict__ A, const unsigned short* __restrict__ Bm,
    void* __restrict__ C, int M, int N, int K, int out_bf16,
    const float* __restrict__ gate, int gate_stride, int batch_shift)
{
    __shared__ unsigned short As[128 * 32];
    __shared__ unsigned short Bs[128 * 32];
    int t = threadIdx.x;
    int w = t >> 6, lane = t & 63;
    int q16 = lane & 15, quad = lane >> 4;
    int wm = w >> 1, wn = w & 1;
    int m0 = blockIdx.y * 128, n0 = blockIdx.x * 128;

    int srow = (w << 5) + (lane >> 2);
    int soff = (lane & 3) << 3;                       // element offset in row
    const unsigned short* ga = A + (size_t)(m0 + srow) * K + soff;
    const unsigned short* gb = Bm + (size_t)(n0 + srow) * K + soff;
    unsigned short* la0 = As + (w << 5) * 32;
    unsigned short* la1 = la0 + 16 * 32;
    unsigned short* lb0 = Bs + (w << 5) * 32;
    unsigned short* lb1 = lb0 + 16 * 32;

    floatx4 acc[4][4];
    #pragma unroll
    for (int mt = 0; mt < 4; ++mt)
        #pragma unroll
        for (int nt = 0; nt < 4; ++nt)
            acc[mt][nt] = (floatx4){0.f, 0.f, 0.f, 0.f};

    int a_row = wm * 64 + q16;
    int b_row = wn * 64 + q16;

    for (int kt = 0; kt < K; kt += 32) {
        __syncthreads();
        gld_lds16(ga, la0);
        gld_lds16(ga + (size_t)16 * K, la1);
        gld_lds16(gb, lb0);
        gld_lds16(gb + (size_t)16 * K, lb1);
        ga += 32; gb += 32;
        __syncthreads();

        short8 af[4], bf[4];
        #pragma unroll
        for (int mt = 0; mt < 4; ++mt)
            af[mt] = *(const short8*)&As[(a_row + mt * 16) * 32 + quad * 8];
        #pragma unroll
        for (int nt = 0; nt < 4; ++nt)
            bf[nt] = *(const short8*)&Bs[(b_row + nt * 16) * 32 + quad * 8];
        #pragma unroll
        for (int mt = 0; mt < 4; ++mt)
            #pragma unroll
            for (int nt = 0; nt < 4; ++nt)
                acc[mt][nt] = __builtin_amdgcn_mfma_f32_16x16x32_bf16(
                    af[mt], bf[nt], acc[mt][nt], 0, 0, 0);
    }

    #pragma unroll
    for (int mt = 0; mt < 4; ++mt) {
        #pragma unroll
        for (int i = 0; i < 4; ++i) {
            int m = m0 + wm * 64 + mt * 16 + quad * 4 + i;
            const float* grow = gate ? gate + (size_t)(m >> batch_shift) * gate_stride
                                     : nullptr;
            #pragma unroll
            for (int nt = 0; nt < 4; ++nt) {
                int n = n0 + wn * 64 + nt * 16 + q16;
                float v = acc[mt][nt][i];
                if (gate) v *= grow[n];
                if (out_bf16)
                    ((unsigned short*)C)[(size_t)m * N + n] =
                        (unsigned short)pk_bf16(v, 0.f);
                else
                    ((float*)C)[(size_t)m * N + n] = v;
            }
        }
    }
}

// ---------------------------------------------------------------------------
// Kernel 4: per-head QK layernorm + RoPE; reads bf16 qkv; emits bf16 q,k
// [bh,S,64] (q pre-scaled by log2(e)/8) and vt [bh,64,S].
// ---------------------------------------------------------------------------
__global__ __launch_bounds__(256) void qk_ln_rope_kernel(
    const unsigned short* __restrict__ qkv, const float* __restrict__ freqs,
    const float* __restrict__ qn_w, const float* __restrict__ kn_w,
    unsigned short* __restrict__ qout, unsigned short* __restrict__ kout,
    unsigned short* __restrict__ vtout)
{
    __shared__ unsigned short vt_lds[64][72];
    int t = threadIdx.x;
    int w = t >> 6, lane = t & 63;
    int bh = blockIdx.x >> 5;          // 32 s-blocks per bh
    int sblk = blockIdx.x & 31;
    int h = bh & (NH_ - 1);
    int b = bh >> 4;

    float qnw = qn_w[lane], knw = kn_w[lane];

    for (int it = 0; it < 16; ++it) {
        int s_local = w * 16 + it;
        int s = sblk * 64 + s_local;
        const unsigned short* base = qkv + ((size_t)(b * S_ + s)) * H3_;
        float qv = bf2f(base[h * HD_ + lane]);
        float kv = bf2f(base[H_ + h * HD_ + lane]);
        unsigned short vv = base[2 * H_ + h * HD_ + lane];

        float qs1 = qv, qs2 = qv * qv, ks1 = kv, ks2 = kv * kv;
        #pragma unroll
        for (int m = 1; m < 64; m <<= 1) {
            qs1 += __shfl_xor(qs1, m); qs2 += __shfl_xor(qs2, m);
            ks1 += __shfl_xor(ks1, m); ks2 += __shfl_xor(ks2, m);
        }
        float qm = qs1 * (1.f / 64), qvar = qs2 * (1.f / 64) - qm * qm;
        float km = ks1 * (1.f / 64), kvar = ks2 * (1.f / 64) - km * km;
        qv = (qv - qm) * rsqrtf(qvar + EPS_) * qnw;
        kv = (kv - km) * rsqrtf(kvar + EPS_) * knw;

        float f0 = freqs[(size_t)s * 64 + (lane >> 1) * 2 + 0];
        float f1 = freqs[(size_t)s * 64 + (lane >> 1) * 2 + 1];
        float qp = __shfl_xor(qv, 1);
        float kp = __shfl_xor(kv, 1);
        float qr = (lane & 1) ? (qv * f0 + qp * f1) : (qv * f0 - qp * f1);
        float kr = (lane & 1) ? (kv * f0 + kp * f1) : (kv * f0 - kp * f1);

        size_t o = ((size_t)bh * S_ + s) * HD_ + lane;
        qout[o] = f2bf(qr * 0.1803368801111244f);  // (1/8)*log2(e)
        kout[o] = f2bf(kr);
        vt_lds[lane][s_local] = vv;
    }
    __syncthreads();
    for (int i = t; i < 512; i += 256) {
        int r = i >> 3, c8 = i & 7;
        *(uint4*)(vtout + ((size_t)bh * 64 + r) * S_ + sblk * 64 + c8 * 8) =
            *(const uint4*)&vt_lds[r][c8 * 8];
    }
}

// ---------------------------------------------------------------------------
// Kernel 5: bf16-MFMA flash attention, STATIC-shift softmax, DOUBLE-BUFFERED
// K/V staging: one barrier per K-tile; tile t+1's global_load_lds issued
// right after the barrier so its latency overlaps tile t's compute (the
// barrier's vmcnt(0) drain only sees loads that aged one full compute phase).
// ---------------------------------------------------------------------------
__global__ __launch_bounds__(256) void attn_mfma_kernel(
    const unsigned short* __restrict__ q, const unsigned short* __restrict__ k,
    const unsigned short* __restrict__ vt, unsigned short* __restrict__ o)
{
    __shared__ unsigned short Ks[2][8 * 544];  // 64 rows, block-padded, x2 buf
    __shared__ unsigned short Vs[2][8 * 544];  // Vs[d][kk], block-padded, x2
    __shared__ unsigned short Ps[4][16][72];   // per-wave staging [query][key|d]

    int t = threadIdx.x;
    int w = t >> 6, lane = t & 63;
    int q16 = lane & 15, quad = lane >> 4;
    int bh = blockIdx.y, b = bh >> 4, h = bh & 15;
    int s0 = blockIdx.x * 64;

    // stage Q tile into Ks[0] (wave w -> 8-row blocks 2w, 2w+1)
    const unsigned short* qg = q + ((size_t)bh * S_ + s0) * HD_;
    gld_lds16(qg + (2 * w) * 512 + lane * 8, &Ks[0][(2 * w) * 544]);
    gld_lds16(qg + (2 * w + 1) * 512 + lane * 8, &Ks[0][(2 * w + 1) * 544]);
    __syncthreads();
    int qrow = TBLK(16 * w + q16);
    short8 qf0 = *(const short8*)&Ks[0][qrow + quad * 8];
    short8 qf1 = *(const short8*)&Ks[0][qrow + 32 + quad * 8];
    __syncthreads();   // all waves' Q-fragment reads done before buf0 reuse

    // ones A-fragment (bf16 1.0 = 0x3F80) for the l-row MFMA
    short8 ones8;
    #pragma unroll
    for (int i = 0; i < 8; ++i) ones8[i] = (short)0x3F80;

    floatx4 acc_o[4];
    floatx4 acc_l = (floatx4){0.f, 0.f, 0.f, 0.f};
    #pragma unroll
    for (int i = 0; i < 4; ++i) acc_o[i] = (floatx4){0.f, 0.f, 0.f, 0.f};

    const unsigned short* kg = k + (size_t)bh * S_ * HD_;
    const unsigned short* vg = vt + (size_t)bh * 64 * S_;
    int vsrc = (16 * w + (lane >> 3)) * S_ + (lane & 7) * 8;
    int ksrc0 = (2 * w) * 512 + lane * 8;
    int ksrc1 = (2 * w + 1) * 512 + lane * 8;

    // preload tile 0 into buffer 0
    gld_lds16(kg + ksrc0, &Ks[0][(2 * w) * 544]);
    gld_lds16(kg + ksrc1, &Ks[0][(2 * w + 1) * 544]);
    gld_lds16(vg + vsrc, &Vs[0][(2 * w) * 544]);
    gld_lds16(vg + vsrc + 8 * S_, &Vs[0][(2 * w + 1) * 544]);

    for (int kt = 0; kt < S_ / 64; ++kt) {
        int cur = kt & 1, nxt = cur ^ 1;
        __syncthreads();   // buf[cur] loads (issued last iter) complete

        if (kt + 1 < S_ / 64) {   // prefetch tile kt+1 into buf[nxt]
            const unsigned short* kg2 = kg + (kt + 1) * (64 * HD_);
            const unsigned short* vg2 = vg + (kt + 1) * 64;
            gld_lds16(kg2 + ksrc0, &Ks[nxt][(2 * w) * 544]);
            gld_lds16(kg2 + ksrc1, &Ks[nxt][(2 * w + 1) * 544]);
            gld_lds16(vg2 + vsrc, &Vs[nxt][(2 * w) * 544]);
            gld_lds16(vg2 + vsrc + 8 * S_, &Vs[nxt][(2 * w + 1) * 544]);
        }

        const unsigned short* ksb = Ks[cur];
        const unsigned short* vsb = Vs[cur];

        // S^T tiles (C-init = -12: static softmax shift folded into MFMA)
        floatx4 sc[4];
        #pragma unroll
        for (int nk = 0; nk < 4; ++nk) sc[nk] = (floatx4){-12.f, -12.f, -12.f, -12.f};
        #pragma unroll
        for (int nk = 0; nk < 4; ++nk) {
            int krow = TBLK(16 * nk + q16);
            short8 kf0 = *(const short8*)&ksb[krow + quad * 8];
            short8 kf1 = *(const short8*)&ksb[krow + 32 + quad * 8];
            sc[nk] = __builtin_amdgcn_mfma_f32_16x16x32_bf16(kf0, qf0, sc[nk], 0, 0, 0);
            sc[nk] = __builtin_amdgcn_mfma_f32_16x16x32_bf16(kf1, qf1, sc[nk], 0, 0, 0);
        }

        // p = exp2(s - 12); raw v_exp_f32; packed bf16 pairs -> b64 write
        #pragma unroll
        for (int nk = 0; nk < 4; ++nk) {
            float p0 = __builtin_amdgcn_exp2f(sc[nk][0]);
            float p1 = __builtin_amdgcn_exp2f(sc[nk][1]);
            float p2 = __builtin_amdgcn_exp2f(sc[nk][2]);
            float p3 = __builtin_amdgcn_exp2f(sc[nk][3]);
            uint2 pk;
            pk.x = pk_bf16(p0, p1);
            pk.y = pk_bf16(p2, p3);
            *(uint2*)&Ps[w][q16][16 * nk + quad * 4] = pk;
        }

        // fence: P writes must not be reordered vs the P fragment reads below
        __asm__ __volatile__("" ::: "memory");

        // O^T += V^T @ P ; l += ones @ P (internal K-reduction gives row sums)
        #pragma unroll
        for (int ks = 0; ks < 2; ++ks) {
            short8 pf = *(const short8*)&Ps[w][q16][ks * 32 + quad * 8];
            acc_l = __builtin_amdgcn_mfma_f32_16x16x32_bf16(ones8, pf, acc_l, 0, 0, 0);
            #pragma unroll
            for (int nd = 0; nd < 4; ++nd) {
                short8 vf = *(const short8*)&vsb[TBLK(16 * nd + q16) + ks * 32 + quad * 8];
                acc_o[nd] = __builtin_amdgcn_mfma_f32_16x16x32_bf16(vf, pf, acc_o[nd], 0, 0, 0);
            }
        }
    }

    // epilogue: l = acc_l[0] (all 4 rows identical); no cross-lane reduction
    float inv = 1.f / acc_l[0];
    #pragma unroll
    for (int nd = 0; nd < 4; ++nd) {
        uint2 pk;
        pk.x = pk_bf16(acc_o[nd][0] * inv, acc_o[nd][1] * inv);
        pk.y = pk_bf16(acc_o[nd][2] * inv, acc_o[nd][3] * inv);
        *(uint2*)&Ps[w][q16][16 * nd + quad * 4] = pk;   // O[query q16][d]
    }
    __asm__ __volatile__("" ::: "memory");
    // store: row = query 16w+q16; 8 chunks of 8 bf16; quad owns chunks 2q,2q+1
    unsigned short* og = o + ((size_t)(b * S_ + s0 + 16 * w + q16)) * H_ + h * HD_;
    #pragma unroll
    for (int i = 0; i < 2; ++i) {
        int c = quad * 2 + i;          // 0..7
        *(short8*)(og + c * 8) = *(const short8*)&Ps[w][q16][c * 8];
    }
}

// ---------------------------------------------------------------------------
extern "C" void kernel_launch(void* const* d_in, const int* in_sizes, int n_in,
                              void* d_out, int out_size, void* d_ws, size_t ws_size,
                              hipStream_t stream)
{
    const float* x     = (const float*)d_in[0];
    const float* ada   = (const float*)d_in[1];
    const float* freqs = (const float*)d_in[2];
    const float* w_qkv = (const float*)d_in[3];
    const float* w_o   = (const float*)d_in[4];
    const float* ln_w  = (const float*)d_in[5];
    const float* mod_w = (const float*)d_in[6];
    const float* mod_b = (const float*)d_in[7];
    const float* qn_w  = (const float*)d_in[8];
    const float* kn_w  = (const float*)d_in[9];
    float* out = (float*)d_out;

    float* ws  = (float*)d_ws;
    float* mod = ws;                                    // 6144 f (pad to 8192)
    unsigned short* qkvb  = (unsigned short*)(mod + 8192);   // B*S*3H bf16
    unsigned short* hb    = qkvb + (size_t)B_ * S_ * H3_;
    unsigned short* qb    = hb + (size_t)B_ * S_ * H_;
    unsigned short* kb    = qb + (size_t)B_ * S_ * H_;
    unsigned short* vtb   = kb + (size_t)B_ * S_ * H_;
    unsigned short* ob    = vtb + (size_t)B_ * S_ * H_;
    unsigned short* wqkvb = ob + (size_t)B_ * S_ * H_;
    unsigned short* wob   = wqkvb + (size_t)H3_ * H_;

    cast_bf16_kernel<<<H3_ * H_ / (8 * 256), 256, 0, stream>>>(w_qkv, wqkvb, H3_ * H_);
    cast_bf16_kernel<<<H_ * H_ / (8 * 256), 256, 0, stream>>>(w_o, wob, H_ * H_);
    mod_gemv_kernel<<<B_ * H3_ / 4, 256, 0, stream>>>(ada, mod_w, mod_b, mod);
    ln_mod_kernel<<<B_ * S_, 256, 0, stream>>>(x, ln_w, mod, hb);
    gemm_bt_bf16_kernel<<<dim3(H3_ / 128, B_ * S_ / 128), 256, 0, stream>>>(
        hb, wqkvb, qkvb, B_ * S_, H3_, H_, 1, nullptr, 0, 0);
    qk_ln_rope_kernel<<<B_ * NH_ * S_ / 64, 256, 0, stream>>>(
        qkvb, freqs, qn_w, kn_w, qb, kb, vtb);
    attn_mfma_kernel<<<dim3(S_ / 64, B_ * NH_), 256, 0, stream>>>(qb, kb, vtb, ob);
    gemm_bt_bf16_kernel<<<dim3(H_ / 128, B_ * S_ / 128), 256, 0, stream>>>(
        ob, wob, out, B_ * S_, H_, H_, 0, mod + 2 * H_, H3_, 11);
}

// Round 11
// 269.973 us; speedup vs baseline: 1.0789x; 1.0789x over previous
//
#include <hip/hip_runtime.h>
#include <hip/hip_bf16.h>
#include <math.h>

// Problem constants
#define B_ 2
#define S_ 2048
#define H_ 1024
#define A_ 1024
#define NH_ 16
#define HD_ 64
#define H3_ 3072
#define EPS_ 1e-5f

typedef __attribute__((ext_vector_type(8))) short short8;   // 8 bf16 in 4 VGPRs
typedef __attribute__((ext_vector_type(4))) float floatx4;  // MFMA accumulator

__device__ inline unsigned short f2bf(float x) {
    union { float f; unsigned u; } v; v.f = x;
    unsigned r = v.u + 0x7fffu + ((v.u >> 16) & 1u);   // RNE
    return (unsigned short)(r >> 16);
}

// packed f32x2 -> bf16x2 (v_cvt_pk_bf16_f32 on gfx950)
__device__ inline unsigned pk_bf16(float a, float b) {
    union { __hip_bfloat162 h; unsigned u; } v;
    v.h = __float22bfloat162_rn(make_float2(a, b));
    return v.u;
}

// async global->LDS, 16B per lane; LDS dst must be wave-uniform base + lane*16
__device__ inline void gld_lds16(const void* g, void* l) {
    __builtin_amdgcn_global_load_lds(
        (const __attribute__((address_space(1))) unsigned int*)g,
        (__attribute__((address_space(3))) unsigned int*)l, 16, 0, 0);
}

// block-padded attention tile layout: 8-row blocks (1024 B) + 64 B pad each.
// row r (0..63), 64 ushorts/row: offset = (r>>3)*544 + (r&7)*64   [ushorts]
#define TBLK(r) ((((r) >> 3) * 544) + (((r) & 7) * 64))

// ---------------------------------------------------------------------------
// Kernel 0: fp32 -> bf16 cast (weights), 8 elems/thread
// ---------------------------------------------------------------------------
__global__ __launch_bounds__(256) void cast_bf16_kernel(
    const float* __restrict__ in, unsigned short* __restrict__ out, int n)
{
    int i = (blockIdx.x * 256 + threadIdx.x) * 8;
    if (i >= n) return;
    float4 a = *(const float4*)(in + i);
    float4 b = *(const float4*)(in + i + 4);
    uint4 o;
    o.x = pk_bf16(a.x, a.y);
    o.y = pk_bf16(a.z, a.w);
    o.z = pk_bf16(b.x, b.y);
    o.w = pk_bf16(b.z, b.w);
    *(uint4*)(out + i) = o;
}

// ---------------------------------------------------------------------------
// Kernel 1: mod = silu(ada_cond) @ mod_w^T + mod_b     [B, 3H]
// ---------------------------------------------------------------------------
__global__ __launch_bounds__(256) void mod_gemv_kernel(
    const float* __restrict__ ada, const float* __restrict__ mod_w,
    const float* __restrict__ mod_b, float* __restrict__ mod)
{
    int wid = threadIdx.x >> 6;
    int lane = threadIdx.x & 63;
    int idx = blockIdx.x * 4 + wid;       // 0 .. B*3H-1
    int b = idx / H3_;
    int j = idx % H3_;
    const float* ar = ada + (size_t)b * A_;
    const float* wr = mod_w + (size_t)j * A_;
    float acc = 0.f;
    for (int a = lane; a < A_; a += 64) {
        float av = ar[a];
        float sv = av / (1.f + __expf(-av));   // silu
        acc += sv * wr[a];
    }
    #pragma unroll
    for (int m = 1; m < 64; m <<= 1) acc += __shfl_xor(acc, m);
    if (lane == 0) mod[idx] = acc + mod_b[j];
}

// ---------------------------------------------------------------------------
// Kernel 2: h = layernorm(x)*ln_w * (scale+1) + shift -> bf16  [B,S,H]
// ---------------------------------------------------------------------------
__global__ __launch_bounds__(256) void ln_mod_kernel(
    const float* __restrict__ x, const float* __restrict__ ln_w,
    const float* __restrict__ mod, unsigned short* __restrict__ hout)
{
    int row = blockIdx.x;          // over B*S
    int b = row >> 11;             // row / 2048
    const float* xr = x + (size_t)row * H_;
    int t = threadIdx.x;
    float4 xv = *(const float4*)(xr + t * 4);
    float s1 = xv.x + xv.y + xv.z + xv.w;
    float s2 = xv.x*xv.x + xv.y*xv.y + xv.z*xv.z + xv.w*xv.w;
    #pragma unroll
    for (int m = 1; m < 64; m <<= 1) { s1 += __shfl_xor(s1, m); s2 += __shfl_xor(s2, m); }
    __shared__ float r1[4], r2[4];
    int wid = t >> 6, lane = t & 63;
    if (lane == 0) { r1[wid] = s1; r2[wid] = s2; }
    __syncthreads();
    s1 = r1[0] + r1[1] + r1[2] + r1[3];
    s2 = r2[0] + r2[1] + r2[2] + r2[3];
    float mean = s1 * (1.f / H_);
    float var  = s2 * (1.f / H_) - mean * mean;
    float rstd = rsqrtf(var + EPS_);
    const float* mrow = mod + (size_t)b * H3_;
    float4 wv = *(const float4*)(ln_w + t * 4);
    float4 sc = *(const float4*)(mrow + t * 4);
    float4 sh = *(const float4*)(mrow + H_ + t * 4);
    float4 hv;
    hv.x = (xv.x - mean) * rstd * wv.x * (sc.x + 1.f) + sh.x;
    hv.y = (xv.y - mean) * rstd * wv.y * (sc.y + 1.f) + sh.y;
    hv.z = (xv.z - mean) * rstd * wv.z * (sc.z + 1.f) + sh.z;
    hv.w = (xv.w - mean) * rstd * wv.w * (sc.w + 1.f) + sh.w;
    uint2 o;
    o.x = pk_bf16(hv.x, hv.y);
    o.y = pk_bf16(hv.z, hv.w);
    *(uint2*)(hout + (size_t)row * H_ + t * 4) = o;
}

// ---------------------------------------------------------------------------
// Kernel 3: QKV GEMM with FUSED qk-LN + RoPE epilogue.
// C-tile per wave = 64 rows (tokens) x 64 cols = exactly ONE head's channels
// (n_base 64-aligned, sections 1024-aligned -> sec/head wave-uniform).
// Row r: held in one quad's 16 lanes x 4 regs -> LN = in-lane + shfl16.
// Q/K: LN (fp32 acc) + RoPE -> bf16 q,k [bh,S,64] (q pre-scaled log2e/8).
// V: packed 4-consecutive-s stores -> vt [bh,64,S].
// ---------------------------------------------------------------------------
__global__ __launch_bounds__(256) void gemm_qkv_fused_kernel(
    const unsigned short* __restrict__ A, const unsigned short* __restrict__ Bm,
    const float* __restrict__ freqs, const float* __restrict__ qn_w,
    const float* __restrict__ kn_w, unsigned short* __restrict__ qout,
    unsigned short* __restrict__ kout, unsigned short* __restrict__ vtout)
{
    __shared__ unsigned short As[128 * 32];
    __shared__ unsigned short Bs[128 * 32];
    const int K = H_, N = H3_;
    int t = threadIdx.x;
    int w = t >> 6, lane = t & 63;
    int q16 = lane & 15, quad = lane >> 4;
    int wm = w >> 1, wn = w & 1;
    int m0 = blockIdx.y * 128, n0 = blockIdx.x * 128;

    int srow = (w << 5) + (lane >> 2);
    int soff = (lane & 3) << 3;
    const unsigned short* ga = A + (size_t)(m0 + srow) * K + soff;
    const unsigned short* gb = Bm + (size_t)(n0 + srow) * K + soff;
    unsigned short* la0 = As + (w << 5) * 32;
    unsigned short* la1 = la0 + 16 * 32;
    unsigned short* lb0 = Bs + (w << 5) * 32;
    unsigned short* lb1 = lb0 + 16 * 32;

    floatx4 acc[4][4];
    #pragma unroll
    for (int mt = 0; mt < 4; ++mt)
        #pragma unroll
        for (int nt = 0; nt < 4; ++nt)
            acc[mt][nt] = (floatx4){0.f, 0.f, 0.f, 0.f};

    int a_row = wm * 64 + q16;
    int b_row = wn * 64 + q16;

    for (int kt = 0; kt < K; kt += 32) {
        __syncthreads();
        gld_lds16(ga, la0);
        gld_lds16(ga + (size_t)16 * K, la1);
        gld_lds16(gb, lb0);
        gld_lds16(gb + (size_t)16 * K, lb1);
        ga += 32; gb += 32;
        __syncthreads();

        short8 af[4], bf[4];
        #pragma unroll
        for (int mt = 0; mt < 4; ++mt)
            af[mt] = *(const short8*)&As[(a_row + mt * 16) * 32 + quad * 8];
        #pragma unroll
        for (int nt = 0; nt < 4; ++nt)
            bf[nt] = *(const short8*)&Bs[(b_row + nt * 16) * 32 + quad * 8];
        #pragma unroll
        for (int mt = 0; mt < 4; ++mt)
            #pragma unroll
            for (int nt = 0; nt < 4; ++nt)
                acc[mt][nt] = __builtin_amdgcn_mfma_f32_16x16x32_bf16(
                    af[mt], bf[nt], acc[mt][nt], 0, 0, 0);
    }

    int n_base = n0 + wn * 64;          // wave-uniform, 64-aligned
    int sec = n_base >> 10;             // 0=Q, 1=K, 2=V
    int head = (n_base & 1023) >> 6;    // 0..15

    if (sec == 2) {
        // V: vt[(b*16+head)*64 + d][s], 4 consecutive s packed per store
        #pragma unroll
        for (int mt = 0; mt < 4; ++mt) {
            int m = m0 + wm * 64 + mt * 16 + quad * 4;
            int b = m >> 11, s = m & (S_ - 1);
            #pragma unroll
            for (int nt = 0; nt < 4; ++nt) {
                int d = nt * 16 + q16;
                unsigned short* dst =
                    vtout + ((size_t)((b * 16 + head) * 64 + d)) * S_ + s;
                uint2 pk;
                pk.x = pk_bf16(acc[mt][nt][0], acc[mt][nt][1]);
                pk.y = pk_bf16(acc[mt][nt][2], acc[mt][nt][3]);
                *(uint2*)dst = pk;
            }
        }
    } else {
        const float* nw = (sec == 0) ? qn_w : kn_w;
        float w4[4];
        #pragma unroll
        for (int nt = 0; nt < 4; ++nt) w4[nt] = nw[nt * 16 + q16];
        unsigned short* outp = (sec == 0) ? qout : kout;
        float qscale = (sec == 0) ? 0.1803368801111244f : 1.0f;  // (1/8)*log2e

        #pragma unroll
        for (int mt = 0; mt < 4; ++mt) {
            #pragma unroll
            for (int i = 0; i < 4; ++i) {
                int m = m0 + wm * 64 + mt * 16 + quad * 4 + i;
                int b = m >> 11, s = m & (S_ - 1);
                float v0 = acc[mt][0][i], v1 = acc[mt][1][i];
                float v2 = acc[mt][2][i], v3 = acc[mt][3][i];
                float s1 = (v0 + v1) + (v2 + v3);
                float s2 = (v0 * v0 + v1 * v1) + (v2 * v2 + v3 * v3);
                #pragma unroll
                for (int msk = 1; msk < 16; msk <<= 1) {
                    s1 += __shfl_xor(s1, msk);
                    s2 += __shfl_xor(s2, msk);
                }
                float mean = s1 * (1.f / 64);
                float var  = s2 * (1.f / 64) - mean * mean;
                float rstd = rsqrtf(var + EPS_);
                float vv[4];
                vv[0] = (v0 - mean) * rstd * w4[0];
                vv[1] = (v1 - mean) * rstd * w4[1];
                vv[2] = (v2 - mean) * rstd * w4[2];
                vv[3] = (v3 - mean) * rstd * w4[3];
                const float* fr = freqs + (size_t)s * 64;
                unsigned short* orow = outp + ((size_t)((b * 16 + head) * S_ + s)) * 64;
                #pragma unroll
                for (int nt = 0; nt < 4; ++nt) {
                    int c = nt * 16 + q16;
                    float vp = __shfl_xor(vv[nt], 1);
                    float2 ff = *(const float2*)(fr + (c & ~1));
                    float r = (c & 1) ? (vv[nt] * ff.x + vp * ff.y)
                                      : (vv[nt] * ff.x - vp * ff.y);
                    orow[c] = f2bf(r * qscale);
                }
            }
        }
    }
}

// ---------------------------------------------------------------------------
// Kernel 6: bf16 MFMA GEMM  C[M,N] = A[M,K] @ B[N,K]^T  (m97 structure),
// fp32 out with per-(batch,col) gate.
// ---------------------------------------------------------------------------
__global__ __launch_bounds__(256) void gemm_bt_bf16_kernel(
    const unsigned short* __restrict__ A, const unsigned short* __restrict__ Bm,
    float* __restrict__ C, int M, int N, int K,
    const float* __restrict__ gate, int gate_stride, int batch_shift)
{
    __shared__ unsigned short As[128 * 32];
    __shared__ unsigned short Bs[128 * 32];
    int t = threadIdx.x;
    int w = t >> 6, lane = t & 63;
    int q16 = lane & 15, quad = lane >> 4;
    int wm = w >> 1, wn = w & 1;
    int m0 = blockIdx.y * 128, n0 = blockIdx.x * 128;

    int srow = (w << 5) + (lane >> 2);
    int soff = (lane & 3) << 3;
    const unsigned short* ga = A + (size_t)(m0 + srow) * K + soff;
    const unsigned short* gb = Bm + (size_t)(n0 + srow) * K + soff;
    unsigned short* la0 = As + (w << 5) * 32;
    unsigned short* la1 = la0 + 16 * 32;
    unsigned short* lb0 = Bs + (w << 5) * 32;
    unsigned short* lb1 = lb0 + 16 * 32;

    floatx4 acc[4][4];
    #pragma unroll
    for (int mt = 0; mt < 4; ++mt)
        #pragma unroll
        for (int nt = 0; nt < 4; ++nt)
            acc[mt][nt] = (floatx4){0.f, 0.f, 0.f, 0.f};

    int a_row = wm * 64 + q16;
    int b_row = wn * 64 + q16;

    for (int kt = 0; kt < K; kt += 32) {
        __syncthreads();
        gld_lds16(ga, la0);
        gld_lds16(ga + (size_t)16 * K, la1);
        gld_lds16(gb, lb0);
        gld_lds16(gb + (size_t)16 * K, lb1);
        ga += 32; gb += 32;
        __syncthreads();

        short8 af[4], bf[4];
        #pragma unroll
        for (int mt = 0; mt < 4; ++mt)
            af[mt] = *(const short8*)&As[(a_row + mt * 16) * 32 + quad * 8];
        #pragma unroll
        for (int nt = 0; nt < 4; ++nt)
            bf[nt] = *(const short8*)&Bs[(b_row + nt * 16) * 32 + quad * 8];
        #pragma unroll
        for (int mt = 0; mt < 4; ++mt)
            #pragma unroll
            for (int nt = 0; nt < 4; ++nt)
                acc[mt][nt] = __builtin_amdgcn_mfma_f32_16x16x32_bf16(
                    af[mt], bf[nt], acc[mt][nt], 0, 0, 0);
    }

    #pragma unroll
    for (int mt = 0; mt < 4; ++mt) {
        #pragma unroll
        for (int i = 0; i < 4; ++i) {
            int m = m0 + wm * 64 + mt * 16 + quad * 4 + i;
            float* crow = C + (size_t)m * N;
            const float* grow = gate ? gate + (size_t)(m >> batch_shift) * gate_stride
                                     : nullptr;
            #pragma unroll
            for (int nt = 0; nt < 4; ++nt) {
                int n = n0 + wn * 64 + nt * 16 + q16;
                float v = acc[mt][nt][i];
                if (gate) v *= grow[n];
                crow[n] = v;
            }
        }
    }
}

// ---------------------------------------------------------------------------
// Kernel 5: bf16-MFMA flash attention, STATIC-shift softmax (round-9 version:
// single-buffer staging — dbuf regressed occupancy 34->24%, m99-style).
// ---------------------------------------------------------------------------
__global__ __launch_bounds__(256) void attn_mfma_kernel(
    const unsigned short* __restrict__ q, const unsigned short* __restrict__ k,
    const unsigned short* __restrict__ vt, unsigned short* __restrict__ o)
{
    __shared__ unsigned short Ks[8 * 544];    // 64 rows, block-padded
    __shared__ unsigned short Vs[8 * 544];    // Vs[d][kk], block-padded
    __shared__ unsigned short Ps[4][16][72];  // per-wave staging [query][key|d]

    int t = threadIdx.x;
    int w = t >> 6, lane = t & 63;
    int q16 = lane & 15, quad = lane >> 4;
    int bh = blockIdx.y, b = bh >> 4, h = bh & 15;
    int s0 = blockIdx.x * 64;

    // stage Q tile (wave w -> 8-row blocks 2w, 2w+1)
    const unsigned short* qg = q + ((size_t)bh * S_ + s0) * HD_;
    gld_lds16(qg + (2 * w) * 512 + lane * 8, &Ks[(2 * w) * 544]);
    gld_lds16(qg + (2 * w + 1) * 512 + lane * 8, &Ks[(2 * w + 1) * 544]);
    __syncthreads();
    int qrow = TBLK(16 * w + q16);
    short8 qf0 = *(const short8*)&Ks[qrow + quad * 8];
    short8 qf1 = *(const short8*)&Ks[qrow + 32 + quad * 8];

    // ones A-fragment (bf16 1.0 = 0x3F80) for the l-row MFMA
    short8 ones8;
    #pragma unroll
    for (int i = 0; i < 8; ++i) ones8[i] = (short)0x3F80;

    floatx4 acc_o[4];
    floatx4 acc_l = (floatx4){0.f, 0.f, 0.f, 0.f};
    #pragma unroll
    for (int i = 0; i < 4; ++i) acc_o[i] = (floatx4){0.f, 0.f, 0.f, 0.f};

    const unsigned short* kg = k + (size_t)bh * S_ * HD_;        // tile kt: += 4096
    const unsigned short* vg = vt + (size_t)bh * 64 * S_;        // tile kt: += 64
    int vsrc = (16 * w + (lane >> 3)) * S_ + (lane & 7) * 8;

    for (int kt = 0; kt < S_ / 64; ++kt) {
        __syncthreads();   // all waves done reading Ks/Vs (and Q frags, iter 0)
        gld_lds16(kg + (2 * w) * 512 + lane * 8, &Ks[(2 * w) * 544]);
        gld_lds16(kg + (2 * w + 1) * 512 + lane * 8, &Ks[(2 * w + 1) * 544]);
        gld_lds16(vg + vsrc, &Vs[(2 * w) * 544]);
        gld_lds16(vg + vsrc + 8 * S_, &Vs[(2 * w + 1) * 544]);
        kg += 64 * HD_;
        vg += 64;
        __syncthreads();

        // S^T tiles (C-init = -12: static softmax shift folded into MFMA)
        floatx4 sc[4];
        #pragma unroll
        for (int nk = 0; nk < 4; ++nk) sc[nk] = (floatx4){-12.f, -12.f, -12.f, -12.f};
        #pragma unroll
        for (int nk = 0; nk < 4; ++nk) {
            int krow = TBLK(16 * nk + q16);
            short8 kf0 = *(const short8*)&Ks[krow + quad * 8];
            short8 kf1 = *(const short8*)&Ks[krow + 32 + quad * 8];
            sc[nk] = __builtin_amdgcn_mfma_f32_16x16x32_bf16(kf0, qf0, sc[nk], 0, 0, 0);
            sc[nk] = __builtin_amdgcn_mfma_f32_16x16x32_bf16(kf1, qf1, sc[nk], 0, 0, 0);
        }

        // p = exp2(s - 12); raw v_exp_f32; packed bf16 pairs -> b64 write
        #pragma unroll
        for (int nk = 0; nk < 4; ++nk) {
            float p0 = __builtin_amdgcn_exp2f(sc[nk][0]);
            float p1 = __builtin_amdgcn_exp2f(sc[nk][1]);
            float p2 = __builtin_amdgcn_exp2f(sc[nk][2]);
            float p3 = __builtin_amdgcn_exp2f(sc[nk][3]);
            uint2 pk;
            pk.x = pk_bf16(p0, p1);
            pk.y = pk_bf16(p2, p3);
            *(uint2*)&Ps[w][q16][16 * nk + quad * 4] = pk;
        }

        // fence: P writes must not be reordered vs the P fragment reads below
        __asm__ __volatile__("" ::: "memory");

        // O^T += V^T @ P ; l += ones @ P (internal K-reduction gives row sums)
        #pragma unroll
        for (int ks = 0; ks < 2; ++ks) {
            short8 pf = *(const short8*)&Ps[w][q16][ks * 32 + quad * 8];
            acc_l = __builtin_amdgcn_mfma_f32_16x16x32_bf16(ones8, pf, acc_l, 0, 0, 0);
            #pragma unroll
            for (int nd = 0; nd < 4; ++nd) {
                short8 vf = *(const short8*)&Vs[TBLK(16 * nd + q16) + ks * 32 + quad * 8];
                acc_o[nd] = __builtin_amdgcn_mfma_f32_16x16x32_bf16(vf, pf, acc_o[nd], 0, 0, 0);
            }
        }
    }

    // epilogue: l = acc_l[0] (all 4 rows identical); no cross-lane reduction
    float inv = 1.f / acc_l[0];
    #pragma unroll
    for (int nd = 0; nd < 4; ++nd) {
        uint2 pk;
        pk.x = pk_bf16(acc_o[nd][0] * inv, acc_o[nd][1] * inv);
        pk.y = pk_bf16(acc_o[nd][2] * inv, acc_o[nd][3] * inv);
        *(uint2*)&Ps[w][q16][16 * nd + quad * 4] = pk;   // O[query q16][d]
    }
    __asm__ __volatile__("" ::: "memory");
    // store: row = query 16w+q16; 8 chunks of 8 bf16; quad owns chunks 2q,2q+1
    unsigned short* og = o + ((size_t)(b * S_ + s0 + 16 * w + q16)) * H_ + h * HD_;
    #pragma unroll
    for (int i = 0; i < 2; ++i) {
        int c = quad * 2 + i;          // 0..7
        *(short8*)(og + c * 8) = *(const short8*)&Ps[w][q16][c * 8];
    }
}

// ---------------------------------------------------------------------------
extern "C" void kernel_launch(void* const* d_in, const int* in_sizes, int n_in,
                              void* d_out, int out_size, void* d_ws, size_t ws_size,
                              hipStream_t stream)
{
    const float* x     = (const float*)d_in[0];
    const float* ada   = (const float*)d_in[1];
    const float* freqs = (const float*)d_in[2];
    const float* w_qkv = (const float*)d_in[3];
    const float* w_o   = (const float*)d_in[4];
    const float* ln_w  = (const float*)d_in[5];
    const float* mod_w = (const float*)d_in[6];
    const float* mod_b = (const float*)d_in[7];
    const float* qn_w  = (const float*)d_in[8];
    const float* kn_w  = (const float*)d_in[9];
    float* out = (float*)d_out;

    float* ws  = (float*)d_ws;
    float* mod = ws;                                    // 6144 f (pad to 8192)
    unsigned short* hb    = (unsigned short*)(mod + 8192);   // B*S*H bf16
    unsigned short* qb    = hb + (size_t)B_ * S_ * H_;
    unsigned short* kb    = qb + (size_t)B_ * S_ * H_;
    unsigned short* vtb   = kb + (size_t)B_ * S_ * H_;
    unsigned short* ob    = vtb + (size_t)B_ * S_ * H_;
    unsigned short* wqkvb = ob + (size_t)B_ * S_ * H_;
    unsigned short* wob   = wqkvb + (size_t)H3_ * H_;

    cast_bf16_kernel<<<H3_ * H_ / (8 * 256), 256, 0, stream>>>(w_qkv, wqkvb, H3_ * H_);
    cast_bf16_kernel<<<H_ * H_ / (8 * 256), 256, 0, stream>>>(w_o, wob, H_ * H_);
    mod_gemv_kernel<<<B_ * H3_ / 4, 256, 0, stream>>>(ada, mod_w, mod_b, mod);
    ln_mod_kernel<<<B_ * S_, 256, 0, stream>>>(x, ln_w, mod, hb);
    gemm_qkv_fused_kernel<<<dim3(H3_ / 128, B_ * S_ / 128), 256, 0, stream>>>(
        hb, wqkvb, freqs, qn_w, kn_w, qb, kb, vtb);
    attn_mfma_kernel<<<dim3(S_ / 64, B_ * NH_), 256, 0, stream>>>(qb, kb, vtb, ob);
    gemm_bt_bf16_kernel<<<dim3(H_ / 128, B_ * S_ / 128), 256, 0, stream>>>(
        ob, wob, out, B_ * S_, H_, H_, mod + 2 * H_, H3_, 11);
}